// Round 21
// baseline (61.703 us; speedup 1.0000x reference)
//
#include <hip/hip_runtime.h>

// CARAFE naive upsample: N=2, C=256, H=100, W=100, K=5, G=1, S=2.
// out[n,c,2h+a,2w+b] = sum_{dy,dx} mask[n,dy*5+dx,2h+a,2w+b] * feat[n,c,h+dy-2,w+dx-2]
//
// Journal: 14 variants stuck 37-40us. Exonerated: occupancy(R11), mask
// latency(R14/R17), VMEM count(R15), mask re-reads(R18), nt-stores(R14/R19),
// bank-swizzles(R20). Shared structure of ALL of them: stage->barrier->
// compute phases + LDS pipe carrying the feature reuse (busiest pipe ~54%).
// R21: remove the structure. Prepass transposes features to channels-last
// ws layout ft[(n*32+cg)*HW + yx][q] (two f4 = 8 ch per pixel, contiguous).
// Main kernel: NO LDS, NO barrier; per tap 2 contiguous f4 loads (12.8KB
// block working set, L1-resident, 25x reuse) + 2 v2f masks + clamp/zero-mask
// + 16 pk-fma. 25 independent taps pipeline freely. Falls back to direct
// strided gather if ws_size too small.

typedef float v2f __attribute__((ext_vector_type(2)));
typedef float v4f __attribute__((ext_vector_type(4)));

#define N_ 2
#define C_ 256
#define H_ 100
#define W_ 100
#define HW_ (H_ * W_)
#define OW_ (W_ * 2)
#define OHW_ (HW_ * 4)
#define CC 8
#define NCHUNK (C_ / CC)          // 32
#define TW 25
#define TH 10
#define TILES_X (W_ / TW)         // 4
#define TILES_Y (H_ / TH)         // 10
#define TILES (TILES_X * TILES_Y) // 40
#define FT_ELEMS (N_ * NCHUNK * HW_ * 2)          // 1.28M f4
#define FT_BYTES ((size_t)FT_ELEMS * 16)          // 20.48 MB

// ---- prepass: channels-last transpose ----
// ft[((n*32+cg)*HW + yx)*2 + q] = {feat[nc8+q4+0..3][yx]}
__global__ __launch_bounds__(256) void transpose_kernel(
    const float* __restrict__ feat, v4f* __restrict__ ft) {
    const int i = blockIdx.x * 256 + threadIdx.x;
    if (i >= FT_ELEMS) return;
    const int q   = i & 1;
    const int tmp = i >> 1;
    const int yx  = tmp % HW_;
    const int nc  = tmp / HW_;               // n*32 + cg
    const float* fb = feat + (nc * CC + q * 4) * HW_ + yx;
    v4f v = { fb[0], fb[HW_], fb[2 * HW_], fb[3 * HW_] };
    ft[i] = v;
}

// ---- main: barrier-free, LDS-free gather ----
template <bool USE_FT>
__global__ __launch_bounds__(256) void carafe_main(
    const v4f* __restrict__ ft, const float* __restrict__ feat,
    const float* __restrict__ mask, float* __restrict__ out) {

    const int cg   = blockIdx.x;             // chunk-fastest (L3 mask sharing)
    const int tile = blockIdx.y;
    const int n    = blockIdx.z;
    const int tx = tile % TILES_X;
    const int ty = tile / TILES_X;
    const int x0 = tx * TW, y0 = ty * TH;
    const int t = threadIdx.x;
    if (t >= TH * TW) return;                // 250 active
    const int hl = t / TW, wl = t % TW;
    const int h = y0 + hl, w = x0 + wl;
    const int oh0 = 2 * h, ow0 = 2 * w;

    const float* mbase = mask + n * (25 * OHW_) + oh0 * OW_ + ow0;
    const v4f* fb = ft + (size_t)(n * NCHUNK + cg) * (HW_ * 2);
    const float* fs = feat + (n * C_ + cg * CC) * HW_;   // fallback path

    v2f a0[CC], a1[CC];
#pragma unroll
    for (int c = 0; c < CC; ++c) { a0[c] = (v2f){0.f, 0.f}; a1[c] = (v2f){0.f, 0.f}; }

#pragma unroll 2
    for (int dy = 0; dy < 5; ++dy) {
        const int y = h + dy - 2;
        const bool yv = (unsigned)y < (unsigned)H_;
        const int yc = min(max(y, 0), H_ - 1);           // v_med3
        const float* mrow = mbase + (dy * 5) * OHW_;
#pragma unroll
        for (int dx = 0; dx < 5; ++dx) {
            const int x = w + dx - 2;
            const bool v = yv && ((unsigned)x < (unsigned)W_);
            const int xc = min(max(x, 0), W_ - 1);

            v2f m0 = *reinterpret_cast<const v2f*>(mrow + dx * OHW_);        // a=0
            v2f m1 = *reinterpret_cast<const v2f*>(mrow + dx * OHW_ + OW_);  // a=1
            if (!v) { m0 = (v2f){0.f, 0.f}; m1 = (v2f){0.f, 0.f}; }

            float f[8];
            if (USE_FT) {
                const int fo = (yc * W_ + xc) * 2;
                const v4f lo = fb[fo];                   // c0..3, 16B contiguous
                const v4f hi = fb[fo + 1];               // c4..7
                f[0] = lo.x; f[1] = lo.y; f[2] = lo.z; f[3] = lo.w;
                f[4] = hi.x; f[5] = hi.y; f[6] = hi.z; f[7] = hi.w;
            } else {
                const int fo = yc * W_ + xc;
#pragma unroll
                for (int c = 0; c < CC; ++c) f[c] = fs[c * HW_ + fo];
            }

#pragma unroll
            for (int c = 0; c < CC; ++c) {
                const v2f fv = {f[c], f[c]};
                a0[c] = __builtin_elementwise_fma(fv, m0, a0[c]);   // v_pk_fma_f32
                a1[c] = __builtin_elementwise_fma(fv, m1, a1[c]);
            }
        }
    }

    float* ob = out + (n * C_ + cg * CC) * OHW_ + oh0 * OW_ + ow0;
#pragma unroll
    for (int c = 0; c < CC; ++c) {
        *reinterpret_cast<v2f*>(ob + c * OHW_) = a0[c];
        *reinterpret_cast<v2f*>(ob + c * OHW_ + OW_) = a1[c];
    }
}

extern "C" void kernel_launch(void* const* d_in, const int* in_sizes, int n_in,
                              void* d_out, int out_size, void* d_ws, size_t ws_size,
                              hipStream_t stream) {
    const float* feat = (const float*)d_in[0];
    const float* mask = (const float*)d_in[1];
    float* out = (float*)d_out;

    dim3 grid(NCHUNK, TILES, N_);            // 32 x 40 x 2 = 2560 blocks

    if (ws_size >= FT_BYTES) {
        v4f* ft = (v4f*)d_ws;
        const int tp_blocks = (FT_ELEMS + 255) / 256;   // 5000
        transpose_kernel<<<tp_blocks, 256, 0, stream>>>(feat, ft);
        carafe_main<true><<<grid, 256, 0, stream>>>(ft, feat, mask, out);
    } else {
        carafe_main<false><<<grid, 256, 0, stream>>>(nullptr, feat, mask, out);
    }
}